// Round 3
// baseline (154.940 us; speedup 1.0000x reference)
//
#include <hip/hip_runtime.h>

constexpr int Bn = 16;
constexpr int Tn = 512;
constexpr int Dn = 256;
constexpr int Vn = 4233;
constexpr int Vp = 4352;   // V padded to 34*128 (rows 4233.. are zeros)
constexpr int Ln = 64;     // LMAX
constexpr int Un = 80;     // glg2 row stride (65 used)
constexpr int CS = 68;     // ctc LDS row stride in floats
constexpr int NCB = 34;    // number of 128-wide vocab column blocks
constexpr int Mtot = Bn * Tn;  // 8192

#define LN2     0.6931471805599453f
#define INV_LN2 1.4426950408889634f

typedef __attribute__((ext_vector_type(8))) short short8;
typedef __attribute__((ext_vector_type(4))) float f32x4;

__device__ __forceinline__ float lg2(float x) { return __builtin_amdgcn_logf(x); }
__device__ __forceinline__ float ex2(float x) { return __builtin_amdgcn_exp2f(x); }

__device__ __forceinline__ unsigned short cvt_bf16(float f) {
    unsigned int u = __float_as_uint(f);
    u = (u + 0x7fffu + ((u >> 16) & 1u)) >> 16;
    return (unsigned short)u;
}

// async global->LDS, 16B per lane; LDS dest contiguous per lane, global addr per-lane
__device__ __forceinline__ void gl_lds16(const void* g, void* l) {
    __builtin_amdgcn_global_load_lds(
        (const __attribute__((address_space(1))) void*)g,
        (__attribute__((address_space(3))) void*)l,
        16, 0, 0);
}

// value from lane-1 (wave_shr:1); lane 0 takes `edge`
__device__ __forceinline__ float dpp_shr1_f(float v, float edge) {
    return __int_as_float(__builtin_amdgcn_update_dpp(
        __float_as_int(edge), __float_as_int(v), 0x138, 0xF, 0xF, false));
}
__device__ __forceinline__ int dpp_shr1_i(int v, int edge) {
    return __builtin_amdgcn_update_dpp(edge, v, 0x138, 0xF, 0xF, false);
}

// ---------------- conversion prep (zeroes out + counters) ----------------
__global__ __launch_bounds__(256) void conv(
    const float* __restrict__ hs, const float* __restrict__ W,
    const float* __restrict__ bias, const int* __restrict__ ys,
    unsigned short* __restrict__ hs_b, unsigned short* __restrict__ w_b,
    float* __restrict__ gbias, float* __restrict__ out, int* __restrict__ cnt)
{
    const int gid = blockIdx.x * 256 + threadIdx.x;
    const int stride = gridDim.x * 256;
    const float4* hs4 = (const float4*)hs;
    const float4* W4  = (const float4*)W;

    if (gid == 0) out[0] = 0.0f;
    if (gid < 128) cnt[gid] = 0;   // [0..63] sep-tile counters, [64..127] gather flags

    for (int i = gid; i < (Bn * Tn * Dn) / 4; i += stride) {
        float4 v = hs4[i];
        ushort4 o = make_ushort4(cvt_bf16(v.x), cvt_bf16(v.y), cvt_bf16(v.z), cvt_bf16(v.w));
        *(ushort4*)(&hs_b[i * 4]) = o;
    }
    for (int i = gid; i < Vp * (Dn / 4); i += stride) {
        int row = i >> 6;
        float4 v = make_float4(0.f, 0.f, 0.f, 0.f);
        if (row < Vn) v = W4[i];
        ushort4 o = make_ushort4(cvt_bf16(v.x), cvt_bf16(v.y), cvt_bf16(v.z), cvt_bf16(v.w));
        *(ushort4*)(&w_b[i * 4]) = o;
    }
    for (int i = gid; i < Bn * 128; i += stride) {
        int b = i >> 7;
        int u = i & 127;
        int v = (u == 0) ? 0 : ((u <= Ln) ? ys[b * Ln + u - 1] : -1);
        gbias[i] = (v >= 0) ? bias[v] : 0.0f;
    }
}

// ---------------- fused GEMM + CTC mega-kernel ----------------
// Block roles (dispatch order = overlap schedule):
//   0..15    : CTC recursion for batch b (round-0 structure: all-wave redundant
//              chain + register prefetch; needs only glg2 = gather-tile output)
//   16..31   : normalizer corr for batch b (needs sep tiles; adds to out directly)
//   32..95   : gather GEMM tiles (one per m-panel P=0..63) -> glg2; flag cnt[64+P]
//   96..2271 : sep GEMM tiles, q-major -> sep; count cnt[P]
__global__ __launch_bounds__(256) void mega(
    const unsigned short* __restrict__ hs_b, const unsigned short* __restrict__ w_b,
    const int* __restrict__ ys, const float* __restrict__ bias,
    const float* __restrict__ gbias, float* __restrict__ sep,
    float* __restrict__ glg2, const int* __restrict__ hlens,
    const int* __restrict__ ylens, float* __restrict__ out,
    int* __restrict__ cnt)
{
    __shared__ __align__(16) union SMem {
        struct { short A[128 * 64]; short Bt[128 * 64]; } g;
        struct {
            float ls[2][64 * CS + 4];
            float shO[64], shE[64], shZ[64];
            int   shX[64];
        } c;
        struct { float half[128]; float wsum[4]; } r;
    } sm;

    const int tid = threadIdx.x;
    const int lane = tid & 63;
    const int w = tid >> 6;

    if (blockIdx.x >= 32) {
        // ================= GEMM role =================
        const int g = blockIdx.x - 32;
        int P, by;
        if (g < 64) { P = g; by = NCB; }                 // gather tile
        else {
            int s = g - 64;
            int q = s / (16 * NCB);
            int rem = s - q * (16 * NCB);
            int bb = rem / NCB;
            by = rem - bb * NCB;
            P = bb * 4 + q;
        }
        const bool gather = (by == NCB);
        const int m0 = P * 128;
        const int mw = w * 32;
        const int b = P >> 2;
        const int lr = lane & 15;
        const int kq = lane >> 4;

        const int srow = lane >> 3;
        const int scg  = (lane & 7) ^ (srow & 7);
        const int scol = scg * 8;

        const unsigned short* bptr[4];
        #pragma unroll
        for (int j = 0; j < 4; ++j) {
            int c = w * 4 + j;
            int row = c * 8 + srow;
            int v;
            if (gather) {
                if (row == 0) v = 0;
                else if (row <= Ln) v = ys[b * Ln + row - 1];
                else v = Vn + 32;                 // zero pad row of w_b
            } else {
                v = by * 128 + row;
            }
            bptr[j] = w_b + (size_t)v * Dn + scol;
        }

        f32x4 acc[2][8];
        #pragma unroll
        for (int mf = 0; mf < 2; ++mf)
            #pragma unroll
            for (int nf = 0; nf < 8; ++nf)
                acc[mf][nf] = (f32x4){0.f, 0.f, 0.f, 0.f};

        for (int ks = 0; ks < 4; ++ks) {
            const int k0 = ks * 64;
            __syncthreads();
            #pragma unroll
            for (int j = 0; j < 4; ++j) {
                int c = w * 4 + j;
                int row = c * 8 + srow;
                gl_lds16(hs_b + (size_t)(m0 + row) * Dn + k0 + scol, (char*)sm.g.A  + c * 1024);
                gl_lds16(bptr[j] + k0,                               (char*)sm.g.Bt + c * 1024);
            }
            __syncthreads();

            #pragma unroll
            for (int sub = 0; sub < 2; ++sub) {
                short8 af[2], bf[8];
                #pragma unroll
                for (int mf = 0; mf < 2; ++mf) {
                    int row = mw + mf * 16 + lr;
                    int cg = (sub * 4 + kq) ^ (row & 7);
                    af[mf] = *(const short8*)(&sm.g.A[row * 64 + cg * 8]);
                }
                #pragma unroll
                for (int nf = 0; nf < 8; ++nf) {
                    int row = nf * 16 + lr;
                    int cg = (sub * 4 + kq) ^ (row & 7);
                    bf[nf] = *(const short8*)(&sm.g.Bt[row * 64 + cg * 8]);
                }
                #pragma unroll
                for (int mf = 0; mf < 2; ++mf)
                    #pragma unroll
                    for (int nf = 0; nf < 8; ++nf)
                        acc[mf][nf] = __builtin_amdgcn_mfma_f32_16x16x32_bf16(
                            af[mf], bf[nf], acc[mf][nf], 0, 0, 0);
            }
        }

        if (!gather) {
            const int n0 = by * 128;
            float bcol[8]; bool valid[8];
            #pragma unroll
            for (int nf = 0; nf < 8; ++nf) {
                int col = n0 + nf * 16 + lr;
                valid[nf] = (col < Vn);
                bcol[nf] = valid[nf] ? bias[col] : 0.0f;
            }
            #pragma unroll
            for (int mf = 0; mf < 2; ++mf) {
                #pragma unroll
                for (int r = 0; r < 4; ++r) {
                    float s = 0.0f;
                    #pragma unroll
                    for (int nf = 0; nf < 8; ++nf)
                        if (valid[nf]) s += __expf(acc[mf][nf][r] + bcol[nf]);
                    #pragma unroll
                    for (int off = 1; off < 16; off <<= 1) s += __shfl_xor(s, off, 64);
                    if (lr == 0)
                        sep[(size_t)by * Mtot + m0 + mw + mf * 16 + kq * 4 + r] = s;
                }
            }
        } else {
            #pragma unroll
            for (int mf = 0; mf < 2; ++mf) {
                #pragma unroll
                for (int nf = 0; nf < 5; ++nf) {
                    int u = nf * 16 + lr;
                    float gv = gbias[b * 128 + u];
                    #pragma unroll
                    for (int r = 0; r < 4; ++r) {
                        int gm = m0 + mw + mf * 16 + kq * 4 + r;
                        glg2[(size_t)gm * Un + u] = (acc[mf][nf][r] + gv) * INV_LN2;
                    }
                }
            }
        }

        // publish completion: barrier drains vmcnt(0); release-agent makes stores visible
        __syncthreads();
        if (tid == 0)
            __hip_atomic_fetch_add(&cnt[gather ? 64 + P : P], 1,
                                   __ATOMIC_RELEASE, __HIP_MEMORY_SCOPE_AGENT);
        return;
    }

    if (blockIdx.x >= 16) {
        // ================= corr (normalizer) role =================
        // corr_b = sum_{t<hl} log2(Z_t); contributes +corr_b*ln2/Bn to out.
        const int b = blockIdx.x - 16;
        const int hl = hlens[b];
        float corrAcc = 0.0f;
        const int tr = tid & 127;

        for (int q = 0; q < 4; ++q) {
            while (__hip_atomic_load(&cnt[b * 4 + q], __ATOMIC_ACQUIRE,
                                     __HIP_MEMORY_SCOPE_AGENT) < NCB)
                __builtin_amdgcn_s_sleep(8);

            int t = q * 128 + tr;
            float s = 0.0f;
            int cb0 = (tid < 128) ? 0 : 17;
            int cb1 = (tid < 128) ? 17 : NCB;
            #pragma unroll
            for (int cb = 0; cb < 17; ++cb) {
                int c = cb0 + cb;
                if (c < cb1) s += sep[(size_t)c * Mtot + b * Tn + t];
            }
            if (tid >= 128) sm.r.half[tr] = s;
            __syncthreads();
            if (tid < 128) {
                float tot = s + sm.r.half[tr];
                if (t < hl) corrAcc += lg2(tot);
            }
            __syncthreads();
        }
        #pragma unroll
        for (int off = 1; off < 64; off <<= 1) corrAcc += __shfl_xor(corrAcc, off, 64);
        if (lane == 0) sm.r.wsum[w] = corrAcc;
        __syncthreads();
        if (tid == 0)
            atomicAdd(out, (sm.r.wsum[0] + sm.r.wsum[1]) * (LN2 / (float)Bn));
        return;
    }

    // ================= CTC role (round-0 structure restored) =================
    // All 4 waves redundantly run the chain (l = lane). Global->reg prefetch of
    // chunk c+1 is issued by the SAME waves before computing chunk c, ex2 applied
    // in-register after compute, LDS write, barrier. Panel-flag spin only gates
    // load issue. setprio(1) wins VALU issue vs co-resident GEMM waves.
    const int b = blockIdx.x;
    const int l = lane;

    const int hl = hlens[b];
    int yl  = ys[b * Ln + l];
    int ylm = (l >= 1) ? ys[b * Ln + l - 1] : -1;
    const float aF = ((l >= 1) && (yl != ylm)) ? 1.0f : 0.0f;

    const float* pm = glg2 + (size_t)b * Tn * Un;

    // wait for gather tile of panel (b,0): rows t=0..127
    while (__hip_atomic_load(&cnt[64 + b * 4], __ATOMIC_ACQUIRE,
                             __HIP_MEMORY_SCOPE_AGENT) < 1)
        __builtin_amdgcn_s_sleep(8);

    // stage chunk 0 (row tt <-> t = 1 + tt), applying exp2 on the fly
    #pragma unroll
    for (int j = 0; j < 4; ++j) {
        int i = tid + j * 256;
        int tt = i >> 4, u4 = (i & 15) * 4;
        float4 v = *(const float4*)(pm + (size_t)(1 + tt) * Un + u4);
        v.x = ex2(v.x); v.y = ex2(v.y); v.z = ex2(v.z); v.w = ex2(v.w);
        *(float4*)(&sm.c.ls[0][tt * CS + u4]) = v;
    }
    if (tid < 64) sm.c.ls[0][tid * CS + 64] = ex2(pm[(size_t)(1 + tid) * Un + 64]);
    __syncthreads();

    // t=0 init (all lanes scale 0); unnormalized
    float o = (l == 0) ? ex2(pm[1]) : 0.0f;
    float e = (l == 0) ? ex2(pm[0]) : 0.0f;
    float z = 0.0f;
    int ex = 0;
    int dn = 0;

    float4 r4a = make_float4(0.f,0.f,0.f,0.f), r4b = r4a, r4c = r4a, r4d = r4a;
    float r1 = 0.0f;

    float qa0, qa1, qa2, qa3, ra0, ra1, ra2, ra3;
    float qb0, qb1, qb2, qb3, rb0, rb1, rb2, rb3;
    float qc0, qc1, qc2, qc3, rc0, rc1, rc2, rc3;

#define RENORM do { \
        float mm = fmaxf(fmaxf(o, e), z); \
        bool nz = (mm > 0.0f); \
        int dd = nz ? ((int)((__float_as_uint(mm) >> 23) & 255u) - 127) : 0; \
        o = ldexpf(o, -dd); e = ldexpf(e, -dd); z = ldexpf(z, -dd); \
        int exT = ex + dd; \
        int xm1 = dpp_shr1_i(exT, -(1 << 28)); \
        int et = nz ? exT : xm1; \
        ex = et; \
        int xet = dpp_shr1_i(et, -(1 << 28)); \
        dn = xet - ex; \
    } while (0)

#define STEPR(qv, rv) do { \
        float om1 = dpp_shr1_f(o, 0.0f); \
        float an  = ldexpf(om1, dn); \
        float nO = fmaf(aF, an, o + e) * (rv); \
        float nE = (e + an) * (qv); \
        float nZ = (z + o) * (qv); \
        o = nO; e = nE; z = nZ; \
    } while (0)

#define LDA(base) do { \
        qa0 = buf[(base) * CS];       ra0 = buf[(base) * CS + 1 + l]; \
        qa1 = buf[((base)+1) * CS];   ra1 = buf[((base)+1) * CS + 1 + l]; \
        qa2 = buf[((base)+2) * CS];   ra2 = buf[((base)+2) * CS + 1 + l]; \
        qa3 = buf[((base)+3) * CS];   ra3 = buf[((base)+3) * CS + 1 + l]; \
    } while (0)
#define LDB(base) do { \
        qb0 = buf[(base) * CS];       rb0 = buf[(base) * CS + 1 + l]; \
        qb1 = buf[((base)+1) * CS];   rb1 = buf[((base)+1) * CS + 1 + l]; \
        qb2 = buf[((base)+2) * CS];   rb2 = buf[((base)+2) * CS + 1 + l]; \
        qb3 = buf[((base)+3) * CS];   rb3 = buf[((base)+3) * CS + 1 + l]; \
    } while (0)
#define LDC(base) do { \
        qc0 = buf[(base) * CS];       rc0 = buf[(base) * CS + 1 + l]; \
        qc1 = buf[((base)+1) * CS];   rc1 = buf[((base)+1) * CS + 1 + l]; \
        qc2 = buf[((base)+2) * CS];   rc2 = buf[((base)+2) * CS + 1 + l]; \
        qc3 = buf[((base)+3) * CS];   rc3 = buf[((base)+3) * CS + 1 + l]; \
    } while (0)

#define W4A do { RENORM; STEPR(qa0,ra0); STEPR(qa1,ra1); STEPR(qa2,ra2); STEPR(qa3,ra3); } while (0)
#define W4B do { RENORM; STEPR(qb0,rb0); STEPR(qb1,rb1); STEPR(qb2,rb2); STEPR(qb3,rb3); } while (0)
#define W4C do { RENORM; STEPR(qc0,rc0); STEPR(qc1,rc1); STEPR(qc2,rc2); STEPR(qc3,rc3); } while (0)

#define STEPS(Joff, ACT) do { \
        RENORM; \
        float q = buf[(Joff) * CS]; \
        float r = buf[(Joff) * CS + 1 + l]; \
        float om1 = dpp_shr1_f(o, 0.0f); \
        float an  = ldexpf(om1, dn); \
        float nO = fmaf(aF, an, o + e) * r; \
        float nE = (e + an) * q; \
        float nZ = (z + o) * q; \
        bool act = (ACT); \
        o = act ? nO : o; e = act ? nE : e; z = act ? nZ : z; \
    } while (0)

    __builtin_amdgcn_s_setprio(1);

    for (int c = 0; c < 8; ++c) {
        if (c < 7) {
            // spin only before issuing loads for chunk c+1 (panel p gathered?)
            int p = (c + 2) >> 1; if (p > 3) p = 3;
            while (__hip_atomic_load(&cnt[64 + b * 4 + p], __ATOMIC_ACQUIRE,
                                     __HIP_MEMORY_SCOPE_AGENT) < 1)
                __builtin_amdgcn_s_sleep(8);

            const int tb = 1 + (c + 1) * 64;
            { int i = tid;       int tt = i >> 4, u4 = (i & 15) * 4;
              r4a = (tb + tt < Tn) ? *(const float4*)(pm + (size_t)(tb + tt) * Un + u4) : make_float4(0.f,0.f,0.f,0.f); }
            { int i = tid + 256; int tt = i >> 4, u4 = (i & 15) * 4;
              r4b = (tb + tt < Tn) ? *(const float4*)(pm + (size_t)(tb + tt) * Un + u4) : make_float4(0.f,0.f,0.f,0.f); }
            { int i = tid + 512; int tt = i >> 4, u4 = (i & 15) * 4;
              r4c = (tb + tt < Tn) ? *(const float4*)(pm + (size_t)(tb + tt) * Un + u4) : make_float4(0.f,0.f,0.f,0.f); }
            { int i = tid + 768; int tt = i >> 4, u4 = (i & 15) * 4;
              r4d = (tb + tt < Tn) ? *(const float4*)(pm + (size_t)(tb + tt) * Un + u4) : make_float4(0.f,0.f,0.f,0.f); }
            if (tid < 64)
                r1 = (tb + tid < Tn) ? pm[(size_t)(tb + tid) * Un + 64] : 0.0f;
        }

        const float* buf = sm.c.ls[c & 1];

        if (c < 7) {
            if (hl >= (c + 1) * 64 + 1) {
                LDA(0); LDB(4);
                LDC(8);  W4A;     // w0  rows 0-3
                LDA(12); W4B;     // w1  rows 4-7
                LDB(16); W4C;     // w2  rows 8-11
                LDC(20); W4A;     // w3  rows 12-15
                LDA(24); W4B;     // w4  rows 16-19
                LDB(28); W4C;     // w5  rows 20-23
                LDC(32); W4A;     // w6  rows 24-27
                LDA(36); W4B;     // w7  rows 28-31
                LDB(40); W4C;     // w8  rows 32-35
                LDC(44); W4A;     // w9  rows 36-39
                LDA(48); W4B;     // w10 rows 40-43
                LDB(52); W4C;     // w11 rows 44-47
                LDC(56); W4A;     // w12 rows 48-51
                LDA(60); W4B;     // w13 rows 52-55
                W4C;              // w14 rows 56-59
                W4A;              // w15 rows 60-63
            } else {
                #pragma unroll 1
                for (int j = 0; j < 64; ++j)
                    STEPS(j, (c * 64 + 1 + j) < hl);
            }
        } else {
            if (hl >= Tn) {
                LDA(0); LDB(4);
                LDC(8);  W4A;
                LDA(12); W4B;
                LDB(16); W4C;
                LDC(20); W4A;
                LDA(24); W4B;
                LDB(28); W4C;
                LDC(32); W4A;
                LDA(36); W4B;
                LDB(40); W4C;
                LDC(44); W4A;
                LDA(48); W4B;
                LDB(52); W4C;
                LDC(56); W4A;
                LDA(60); W4B;
                W4C;                               // w14 rows 56-59
                RENORM;                            // partial w15: rows 60-62
                STEPR(qa0, ra0); STEPR(qa1, ra1); STEPR(qa2, ra2);
            } else {
                #pragma unroll 1
                for (int j = 0; j < 63; ++j)
                    STEPS(j, (449 + j) < hl);
            }
        }

        if (c < 7) {
            const int tb = 1 + (c + 1) * 64;
            float* dst = sm.c.ls[(c + 1) & 1];
            { int i = tid;       int tt = i >> 4, u4 = (i & 15) * 4; float4 v = r4a;
              if (tb + tt < Tn) { v.x = ex2(v.x); v.y = ex2(v.y); v.z = ex2(v.z); v.w = ex2(v.w); }
              else v = make_float4(0.f,0.f,0.f,0.f);
              *(float4*)(&dst[tt * CS + u4]) = v; }
            { int i = tid + 256; int tt = i >> 4, u4 = (i & 15) * 4; float4 v = r4b;
              if (tb + tt < Tn) { v.x = ex2(v.x); v.y = ex2(v.y); v.z = ex2(v.z); v.w = ex2(v.w); }
              else v = make_float4(0.f,0.f,0.f,0.f);
              *(float4*)(&dst[tt * CS + u4]) = v; }
            { int i = tid + 512; int tt = i >> 4, u4 = (i & 15) * 4; float4 v = r4c;
              if (tb + tt < Tn) { v.x = ex2(v.x); v.y = ex2(v.y); v.z = ex2(v.z); v.w = ex2(v.w); }
              else v = make_float4(0.f,0.f,0.f,0.f);
              *(float4*)(&dst[tt * CS + u4]) = v; }
            { int i = tid + 768; int tt = i >> 4, u4 = (i & 15) * 4; float4 v = r4d;
              if (tb + tt < Tn) { v.x = ex2(v.x); v.y = ex2(v.y); v.z = ex2(v.z); v.w = ex2(v.w); }
              else v = make_float4(0.f,0.f,0.f,0.f);
              *(float4*)(&dst[tt * CS + u4]) = v; }
            if (tid < 64)
                dst[tid * CS + 64] = (tb + tid < Tn) ? ex2(r1) : 0.0f;
        }
        __syncthreads();
    }

    __builtin_amdgcn_s_setprio(0);
#undef RENORM
#undef STEPR
#undef LDA
#undef LDB
#undef LDC
#undef W4A
#undef W4B
#undef W4C
#undef STEPS

    if (tid < 64) { sm.c.shO[l] = o; sm.c.shE[l] = e; sm.c.shZ[l] = z; sm.c.shX[l] = ex; }
    __syncthreads();

    if (tid == 0) {
        int L = ylens[b];
        float vo = sm.c.shO[L - 1]; int xo = sm.c.shX[L - 1];   // alpha[2L-1]
        float ve; int xe;                                        // alpha[2L]
        if (L == 64) { ve = sm.c.shZ[63]; xe = sm.c.shX[63]; }
        else         { ve = sm.c.shE[L];  xe = sm.c.shX[L]; }
        int em = (xo > xe) ? xo : xe;
        float s = ldexpf(vo, xo - em) + ldexpf(ve, xe - em);
        float ll = (lg2(s) + (float)em) * LN2;
        atomicAdd(out, -ll / (float)Bn);
    }
}

extern "C" void kernel_launch(void* const* d_in, const int* in_sizes, int n_in,
                              void* d_out, int out_size, void* d_ws, size_t ws_size,
                              hipStream_t stream) {
    const float* hs    = (const float*)d_in[0];
    const int*   hlens = (const int*)d_in[1];
    const int*   ys    = (const int*)d_in[2];
    const int*   ylens = (const int*)d_in[3];
    const float* W     = (const float*)d_in[4];
    const float* bias  = (const float*)d_in[5];
    float* out = (float*)d_out;

    char* ws = (char*)d_ws;
    unsigned short* hs_b = (unsigned short*)(ws);                       // 4,194,304 B
    unsigned short* w_b  = (unsigned short*)(ws + 4194304);             // 2,228,224 B
    float* glg2  = (float*)(ws + 6422528);                              // 2,621,440 B
    float* sep   = (float*)(ws + 9043968);                              // 1,114,112 B
    float* gbias = (float*)(ws + 10158080);                             //     8,192 B
    int*   cnt   = (int*)(ws + 10166272);                               //       512 B

    conv<<<1024, 256, 0, stream>>>(hs, W, bias, ys, hs_b, w_b, gbias, out, cnt);
    // 32 (ctc+corr) + 64 (gather) + 64*34 (sep tiles, q-major) = 2272 blocks
    mega<<<32 + 64 + 64 * NCB, 256, 0, stream>>>(
        hs_b, w_b, ys, bias, gbias, sep, glg2, hlens, ylens, out, cnt);
}

// Round 4
// 121.101 us; speedup vs baseline: 1.2794x; 1.2794x over previous
//
#include <hip/hip_runtime.h>

constexpr int Bn = 16;
constexpr int Tn = 512;
constexpr int Dn = 256;
constexpr int Vn = 4233;
constexpr int Vp = 4352;   // V padded to 34*128 (rows 4233.. are zeros)
constexpr int Ln = 64;     // LMAX
constexpr int Un = 80;     // glg2/pmat row stride (65 used)
constexpr int CS = 68;     // ctc LDS row stride in floats
constexpr int NCB = 34;    // number of 128-wide vocab column blocks
constexpr int Mtot = Bn * Tn;  // 8192

#define LN2     0.6931471805599453f
#define INV_LN2 1.4426950408889634f

typedef __attribute__((ext_vector_type(8))) short short8;
typedef __attribute__((ext_vector_type(4))) float f32x4;

__device__ __forceinline__ float lg2(float x) { return __builtin_amdgcn_logf(x); }
__device__ __forceinline__ float ex2(float x) { return __builtin_amdgcn_exp2f(x); }

__device__ __forceinline__ unsigned short cvt_bf16(float f) {
    unsigned int u = __float_as_uint(f);
    u = (u + 0x7fffu + ((u >> 16) & 1u)) >> 16;
    return (unsigned short)u;
}

// async global->LDS, 16B per lane; LDS dest contiguous per lane, global addr per-lane
__device__ __forceinline__ void gl_lds16(const void* g, void* l) {
    __builtin_amdgcn_global_load_lds(
        (const __attribute__((address_space(1))) void*)g,
        (__attribute__((address_space(3))) void*)l,
        16, 0, 0);
}

// f64 value from lane-1 (wave_shr:1); lane 0 takes 0.0
__device__ __forceinline__ double dpp_shr1_d(double v) {
    union { double d; int i[2]; } u, r;
    u.d = v;
    r.i[0] = __builtin_amdgcn_update_dpp(0, u.i[0], 0x138, 0xF, 0xF, false);
    r.i[1] = __builtin_amdgcn_update_dpp(0, u.i[1], 0x138, 0xF, 0xF, false);
    return r.d;
}

// wave-wide int max -> uniform value in all lanes (4 DPP stages + 4 readlanes)
__device__ __forceinline__ int wave_imax(int v) {
    int t;
    t = __builtin_amdgcn_update_dpp(v, v, 0xB1,  0xF, 0xF, false); v = (t > v) ? t : v; // quad_perm [1,0,3,2] : xor1
    t = __builtin_amdgcn_update_dpp(v, v, 0x4E,  0xF, 0xF, false); v = (t > v) ? t : v; // quad_perm [2,3,0,1] : xor2
    t = __builtin_amdgcn_update_dpp(v, v, 0x141, 0xF, 0xF, false); v = (t > v) ? t : v; // row_half_mirror : xor4
    t = __builtin_amdgcn_update_dpp(v, v, 0x140, 0xF, 0xF, false); v = (t > v) ? t : v; // row_mirror : xor8
    int a = __builtin_amdgcn_readlane(v, 0);
    int b = __builtin_amdgcn_readlane(v, 16);
    int c = __builtin_amdgcn_readlane(v, 32);
    int d = __builtin_amdgcn_readlane(v, 48);
    int ab = (a > b) ? a : b;
    int cd = (c > d) ? c : d;
    return (ab > cd) ? ab : cd;
}

// ---------------- conversion prep (zeroes d_out) ----------------
__global__ __launch_bounds__(256) void conv(
    const float* __restrict__ hs, const float* __restrict__ W,
    const float* __restrict__ bias, const int* __restrict__ ys,
    unsigned short* __restrict__ hs_b, unsigned short* __restrict__ w_b,
    float* __restrict__ gbias, float* __restrict__ out)
{
    const int gid = blockIdx.x * 256 + threadIdx.x;
    const int stride = gridDim.x * 256;
    const float4* hs4 = (const float4*)hs;
    const float4* W4  = (const float4*)W;

    if (gid == 0) out[0] = 0.0f;   // atomic target for ctc_fwd

    for (int i = gid; i < (Bn * Tn * Dn) / 4; i += stride) {
        float4 v = hs4[i];
        ushort4 o = make_ushort4(cvt_bf16(v.x), cvt_bf16(v.y), cvt_bf16(v.z), cvt_bf16(v.w));
        *(ushort4*)(&hs_b[i * 4]) = o;
    }
    for (int i = gid; i < Vp * (Dn / 4); i += stride) {
        int row = i >> 6;
        float4 v = make_float4(0.f, 0.f, 0.f, 0.f);
        if (row < Vn) v = W4[i];
        ushort4 o = make_ushort4(cvt_bf16(v.x), cvt_bf16(v.y), cvt_bf16(v.z), cvt_bf16(v.w));
        *(ushort4*)(&w_b[i * 4]) = o;
    }
    for (int i = gid; i < Bn * 128; i += stride) {
        int b = i >> 7;
        int u = i & 127;
        int v = (u == 0) ? 0 : ((u <= Ln) ? ys[b * Ln + u - 1] : -1);
        gbias[i] = (v >= 0) ? bias[v] : 0.0f;
    }
}

// ---------------- unified GEMM ----------------
__global__ __launch_bounds__(256) void gemm_se(
    const unsigned short* __restrict__ hs_b, const unsigned short* __restrict__ w_b,
    const int* __restrict__ ys, const float* __restrict__ bias,
    const float* __restrict__ gbias, float* __restrict__ sep,
    float* __restrict__ glg2)
{
    __shared__ __align__(16) short lsA[128 * 64];
    __shared__ __align__(16) short lsB[128 * 64];

    const int tid = threadIdx.x;
    const int lane = tid & 63;
    const int w = tid >> 6;
    const int lr = lane & 15;
    const int kq = lane >> 4;
    const int m0 = blockIdx.x * 128;
    const int mw = w * 32;
    const bool gather = (blockIdx.y == NCB);
    const int b = blockIdx.x >> 2;

    const int srow = lane >> 3;
    const int scg  = (lane & 7) ^ (srow & 7);
    const int scol = scg * 8;

    const unsigned short* bptr[4];
    #pragma unroll
    for (int j = 0; j < 4; ++j) {
        int c = w * 4 + j;
        int row = c * 8 + srow;
        int v;
        if (gather) {
            if (row == 0) v = 0;
            else if (row <= Ln) v = ys[b * Ln + row - 1];
            else v = Vn + 32;                 // zero pad row of w_b
        } else {
            v = blockIdx.y * 128 + row;
        }
        bptr[j] = w_b + (size_t)v * Dn + scol;
    }

    f32x4 acc[2][8];
    #pragma unroll
    for (int mf = 0; mf < 2; ++mf)
        #pragma unroll
        for (int nf = 0; nf < 8; ++nf)
            acc[mf][nf] = (f32x4){0.f, 0.f, 0.f, 0.f};

    for (int ks = 0; ks < 4; ++ks) {
        const int k0 = ks * 64;
        __syncthreads();
        #pragma unroll
        for (int j = 0; j < 4; ++j) {
            int c = w * 4 + j;
            int row = c * 8 + srow;
            gl_lds16(hs_b + (size_t)(m0 + row) * Dn + k0 + scol, (char*)lsA + c * 1024);
            gl_lds16(bptr[j] + k0,                               (char*)lsB + c * 1024);
        }
        __syncthreads();

        #pragma unroll
        for (int sub = 0; sub < 2; ++sub) {
            short8 af[2], bf[8];
            #pragma unroll
            for (int mf = 0; mf < 2; ++mf) {
                int row = mw + mf * 16 + lr;
                int cg = (sub * 4 + kq) ^ (row & 7);
                af[mf] = *(const short8*)(&lsA[row * 64 + cg * 8]);
            }
            #pragma unroll
            for (int nf = 0; nf < 8; ++nf) {
                int row = nf * 16 + lr;
                int cg = (sub * 4 + kq) ^ (row & 7);
                bf[nf] = *(const short8*)(&lsB[row * 64 + cg * 8]);
            }
            #pragma unroll
            for (int mf = 0; mf < 2; ++mf)
                #pragma unroll
                for (int nf = 0; nf < 8; ++nf)
                    acc[mf][nf] = __builtin_amdgcn_mfma_f32_16x16x32_bf16(
                        af[mf], bf[nf], acc[mf][nf], 0, 0, 0);
        }
    }

    if (!gather) {
        const int n0 = blockIdx.y * 128;
        float bcol[8]; bool valid[8];
        #pragma unroll
        for (int nf = 0; nf < 8; ++nf) {
            int col = n0 + nf * 16 + lr;
            valid[nf] = (col < Vn);
            bcol[nf] = valid[nf] ? bias[col] : 0.0f;
        }
        #pragma unroll
        for (int mf = 0; mf < 2; ++mf) {
            #pragma unroll
            for (int r = 0; r < 4; ++r) {
                float s = 0.0f;
                #pragma unroll
                for (int nf = 0; nf < 8; ++nf)
                    if (valid[nf]) s += __expf(acc[mf][nf][r] + bcol[nf]);
                #pragma unroll
                for (int off = 1; off < 16; off <<= 1) s += __shfl_xor(s, off, 64);
                if (lr == 0)
                    sep[(size_t)blockIdx.y * Mtot + m0 + mw + mf * 16 + kq * 4 + r] = s;
            }
        }
    } else {
        #pragma unroll
        for (int mf = 0; mf < 2; ++mf) {
            #pragma unroll
            for (int nf = 0; nf < 5; ++nf) {
                int u = nf * 16 + lr;
                float gv = gbias[b * 128 + u];
                #pragma unroll
                for (int r = 0; r < 4; ++r) {
                    int g = m0 + mw + mf * 16 + kq * 4 + r;
                    glg2[(size_t)g * Un + u] = (acc[mf][nf][r] + gv) * INV_LN2;
                }
            }
        }
    }
}

// ---------------- lse + in-place normalize: glg2 <- exp2(glg2 - log2 sum) ----
__global__ __launch_bounds__(256) void lse_norm(
    const float* __restrict__ sep, float* __restrict__ glg2)
{
    __shared__ float sl[64];
    const int tid = threadIdx.x;
    const int g0 = blockIdx.x * 64;

    if (tid < 64) {
        float s = 0.0f;
        #pragma unroll
        for (int c = 0; c < NCB; ++c) s += sep[(size_t)c * Mtot + g0 + tid];
        sl[tid] = lg2(s);
    }
    __syncthreads();

    #pragma unroll
    for (int j = 0; j < 4; ++j) {
        int i = tid + j * 256;
        int row = i >> 4, u4 = (i & 15) * 4;
        float* p = glg2 + (size_t)(g0 + row) * Un + u4;
        float4 v = *(const float4*)p;
        float sub = sl[row];
        v.x = ex2(v.x - sub); v.y = ex2(v.y - sub);
        v.z = ex2(v.z - sub); v.w = ex2(v.w - sub);
        *(float4*)p = v;
    }
    if (tid < 64) {
        float* p = glg2 + (size_t)(g0 + tid) * Un + 64;
        *p = ex2(*p - sl[tid]);
    }
}

// ---------------- CTC forward recursion (f64, wave-uniform scale) ----------------
// alpha in double precision: 32 steps shrink the row max by ~2^-413 (per-step
// floor = blank prob ~2^-13), comfortably inside f64 range -> renorm only every
// 32 steps, by a WAVE-UNIFORM scale (DPP butterfly max of per-lane exponents).
// This removes the per-lane exponent machinery (dn, int DPPs, ldexp-per-step)
// from the dependent chain: STEPR = dpp -> add/fma -> mul only.
__global__ __launch_bounds__(256) void ctc_fwd(
    const float* __restrict__ pmat, const int* __restrict__ ys,
    const int* __restrict__ hlens, const int* __restrict__ ylens,
    float* __restrict__ out)
{
    __shared__ float ls[2][64 * CS + 4];
    __shared__ double shO[64], shE[64], shZ[64];
    __shared__ int   shX[64];

    const int b = blockIdx.x;
    const int tid = threadIdx.x;
    const int l = tid & 63;

    const int hl = hlens[b];
    int yl  = ys[b * Ln + l];
    int ylm = (l >= 1) ? ys[b * Ln + l - 1] : -1;
    const double aF = ((l >= 1) && (yl != ylm)) ? 1.0 : 0.0;

    const float* pm = pmat + (size_t)b * Tn * Un;

    // stage chunk 0 (row tt <-> t = 1 + tt)
    #pragma unroll
    for (int j = 0; j < 4; ++j) {
        int i = tid + j * 256;
        int tt = i >> 4, u4 = (i & 15) * 4;
        *(float4*)(&ls[0][tt * CS + u4]) = *(const float4*)(pm + (size_t)(1 + tt) * Un + u4);
    }
    if (tid < 64) ls[0][tid * CS + 64] = pm[(size_t)(1 + tid) * Un + 64];
    __syncthreads();

    // t=0 init (uniform scale 0)
    double o = (l == 0) ? (double)pm[1] : 0.0;
    double e = (l == 0) ? (double)pm[0] : 0.0;
    double z = 0.0;
    int ex = 0;

    float4 r4a = make_float4(0.f,0.f,0.f,0.f), r4b = r4a, r4c = r4a, r4d = r4a;
    float r1 = 0.0f;

    double qa0, qa1, qa2, qa3, ra0, ra1, ra2, ra3;
    double qb0, qb1, qb2, qb3, rb0, rb1, rb2, rb3;
    double qc0, qc1, qc2, qc3, rc0, rc1, rc2, rc3;

// wave-uniform renorm: scale all lanes by 2^-km, km = max lane exponent
#define RENORM32 do { \
        double mm = fmax(fmax(o, e), z); \
        union { double d; unsigned int ui[2]; } um; um.d = mm; \
        int kk = (int)((um.ui[1] >> 20) & 2047u) - 1023; \
        int km = wave_imax(kk); \
        o = ldexp(o, -km); e = ldexp(e, -km); z = ldexp(z, -km); \
        ex += km; \
    } while (0)

#define STEPR(qv, rv) do { \
        double an = dpp_shr1_d(o); \
        double nO = fma(aF, an, o + e) * (rv); \
        double nE = (e + an) * (qv); \
        double nZ = (z + o) * (qv); \
        o = nO; e = nE; z = nZ; \
    } while (0)

#define LDA(base) do { \
        qa0 = (double)buf[(base) * CS];       ra0 = (double)buf[(base) * CS + 1 + l]; \
        qa1 = (double)buf[((base)+1) * CS];   ra1 = (double)buf[((base)+1) * CS + 1 + l]; \
        qa2 = (double)buf[((base)+2) * CS];   ra2 = (double)buf[((base)+2) * CS + 1 + l]; \
        qa3 = (double)buf[((base)+3) * CS];   ra3 = (double)buf[((base)+3) * CS + 1 + l]; \
    } while (0)
#define LDB(base) do { \
        qb0 = (double)buf[(base) * CS];       rb0 = (double)buf[(base) * CS + 1 + l]; \
        qb1 = (double)buf[((base)+1) * CS];   rb1 = (double)buf[((base)+1) * CS + 1 + l]; \
        qb2 = (double)buf[((base)+2) * CS];   rb2 = (double)buf[((base)+2) * CS + 1 + l]; \
        qb3 = (double)buf[((base)+3) * CS];   rb3 = (double)buf[((base)+3) * CS + 1 + l]; \
    } while (0)
#define LDC(base) do { \
        qc0 = (double)buf[(base) * CS];       rc0 = (double)buf[(base) * CS + 1 + l]; \
        qc1 = (double)buf[((base)+1) * CS];   rc1 = (double)buf[((base)+1) * CS + 1 + l]; \
        qc2 = (double)buf[((base)+2) * CS];   rc2 = (double)buf[((base)+2) * CS + 1 + l]; \
        qc3 = (double)buf[((base)+3) * CS];   rc3 = (double)buf[((base)+3) * CS + 1 + l]; \
    } while (0)

#define W4A do { STEPR(qa0,ra0); STEPR(qa1,ra1); STEPR(qa2,ra2); STEPR(qa3,ra3); } while (0)
#define W4B do { STEPR(qb0,rb0); STEPR(qb1,rb1); STEPR(qb2,rb2); STEPR(qb3,rb3); } while (0)
#define W4C do { STEPR(qc0,rc0); STEPR(qc1,rc1); STEPR(qc2,rc2); STEPR(qc3,rc3); } while (0)

// predicated fallback step (partial chunks; never taken when hl == Tn).
// Renorm every step (cheap enough for the rare path). Frozen lanes still get
// scaled, but ex compensates exactly at readout, so freezing is preserved.
#define STEPS(Joff, ACT) do { \
        RENORM32; \
        double q = (double)buf[(Joff) * CS]; \
        double r = (double)buf[(Joff) * CS + 1 + l]; \
        double an = dpp_shr1_d(o); \
        double nO = fma(aF, an, o + e) * r; \
        double nE = (e + an) * q; \
        double nZ = (z + o) * q; \
        bool act = (ACT); \
        o = act ? nO : o; e = act ? nE : e; z = act ? nZ : z; \
    } while (0)

    for (int c = 0; c < 8; ++c) {
        if (c < 7) {
            const int tb = 1 + (c + 1) * 64;
            { int i = tid;       int tt = i >> 4, u4 = (i & 15) * 4;
              r4a = (tb + tt < Tn) ? *(const float4*)(pm + (size_t)(tb + tt) * Un + u4) : make_float4(0.f,0.f,0.f,0.f); }
            { int i = tid + 256; int tt = i >> 4, u4 = (i & 15) * 4;
              r4b = (tb + tt < Tn) ? *(const float4*)(pm + (size_t)(tb + tt) * Un + u4) : make_float4(0.f,0.f,0.f,0.f); }
            { int i = tid + 512; int tt = i >> 4, u4 = (i & 15) * 4;
              r4c = (tb + tt < Tn) ? *(const float4*)(pm + (size_t)(tb + tt) * Un + u4) : make_float4(0.f,0.f,0.f,0.f); }
            { int i = tid + 768; int tt = i >> 4, u4 = (i & 15) * 4;
              r4d = (tb + tt < Tn) ? *(const float4*)(pm + (size_t)(tb + tt) * Un + u4) : make_float4(0.f,0.f,0.f,0.f); }
            if (tid < 64)
                r1 = (tb + tid < Tn) ? pm[(size_t)(tb + tid) * Un + 64] : 0.0f;
        }

        const float* buf = ls[c & 1];

        if (c < 7) {
            if (hl >= (c + 1) * 64 + 1) {
                RENORM32;
                LDA(0); LDB(4);
                LDC(8);  W4A;     // w0  rows 0-3
                LDA(12); W4B;     // w1  rows 4-7
                LDB(16); W4C;     // w2  rows 8-11
                LDC(20); W4A;     // w3  rows 12-15
                LDA(24); W4B;     // w4  rows 16-19
                LDB(28); W4C;     // w5  rows 20-23
                LDC(32); W4A;     // w6  rows 24-27
                LDA(36); W4B;     // w7  rows 28-31
                RENORM32;
                LDB(40); W4C;     // w8  rows 32-35
                LDC(44); W4A;     // w9  rows 36-39
                LDA(48); W4B;     // w10 rows 40-43
                LDB(52); W4C;     // w11 rows 44-47
                LDC(56); W4A;     // w12 rows 48-51
                LDA(60); W4B;     // w13 rows 52-55
                W4C;              // w14 rows 56-59
                W4A;              // w15 rows 60-63
            } else {
                #pragma unroll 1
                for (int j = 0; j < 64; ++j)
                    STEPS(j, (c * 64 + 1 + j) < hl);
            }
        } else {
            if (hl >= Tn) {
                RENORM32;
                LDA(0); LDB(4);
                LDC(8);  W4A;
                LDA(12); W4B;
                LDB(16); W4C;
                LDC(20); W4A;
                LDA(24); W4B;
                LDB(28); W4C;
                LDC(32); W4A;
                LDA(36); W4B;
                RENORM32;
                LDB(40); W4C;
                LDC(44); W4A;
                LDA(48); W4B;
                LDB(52); W4C;
                LDC(56); W4A;
                LDA(60); W4B;
                W4C;                               // w14 rows 56-59
                STEPR(qa0, ra0); STEPR(qa1, ra1); STEPR(qa2, ra2);  // rows 60-62
            } else {
                #pragma unroll 1
                for (int j = 0; j < 63; ++j)
                    STEPS(j, (449 + j) < hl);
            }
        }

        if (c < 7) {
            float* dst = ls[(c + 1) & 1];
            { int i = tid;       int tt = i >> 4, u4 = (i & 15) * 4; *(float4*)(&dst[tt * CS + u4]) = r4a; }
            { int i = tid + 256; int tt = i >> 4, u4 = (i & 15) * 4; *(float4*)(&dst[tt * CS + u4]) = r4b; }
            { int i = tid + 512; int tt = i >> 4, u4 = (i & 15) * 4; *(float4*)(&dst[tt * CS + u4]) = r4c; }
            { int i = tid + 768; int tt = i >> 4, u4 = (i & 15) * 4; *(float4*)(&dst[tt * CS + u4]) = r4d; }
            if (tid < 64) dst[tid * CS + 64] = r1;
        }
        __syncthreads();
    }
#undef RENORM32
#undef STEPR
#undef LDA
#undef LDB
#undef LDC
#undef W4A
#undef W4B
#undef W4C
#undef STEPS

    if (tid < 64) { shO[l] = o; shE[l] = e; shZ[l] = z; shX[l] = ex; }
    __syncthreads();

    if (tid == 0) {
        int L = ylens[b];
        double vo = shO[L - 1]; int xo = shX[L - 1];     // alpha[2L-1]
        double ve; int xe;                                // alpha[2L]
        if (L == 64) { ve = shZ[63]; xe = shX[63]; }
        else         { ve = shE[L];  xe = shX[L]; }
        int em = (xo > xe) ? xo : xe;                     // (scales are uniform, but stay general)
        double s = ldexp(vo, xo - em) + ldexp(ve, xe - em);
        union { double d; unsigned int ui[2]; } us; us.d = s;
        int ks = (int)((us.ui[1] >> 20) & 2047u) - 1023;
        double mant = ldexp(s, -ks);                      // in [1,2)
        float ll = (lg2((float)mant) + (float)(ks + em)) * LN2;
        atomicAdd(out, -ll / (float)Bn);
    }
}

extern "C" void kernel_launch(void* const* d_in, const int* in_sizes, int n_in,
                              void* d_out, int out_size, void* d_ws, size_t ws_size,
                              hipStream_t stream) {
    const float* hs    = (const float*)d_in[0];
    const int*   hlens = (const int*)d_in[1];
    const int*   ys    = (const int*)d_in[2];
    const int*   ylens = (const int*)d_in[3];
    const float* W     = (const float*)d_in[4];
    const float* bias  = (const float*)d_in[5];
    float* out = (float*)d_out;

    char* ws = (char*)d_ws;
    unsigned short* hs_b = (unsigned short*)(ws);                       // 4,194,304 B
    unsigned short* w_b  = (unsigned short*)(ws + 4194304);             // 2,228,224 B
    float* glg2  = (float*)(ws + 6422528);                              // 2,621,440 B
    float* sep   = (float*)(ws + 9043968);                              // 1,114,112 B
    float* gbias = (float*)(ws + 10158080);                             //     8,192 B

    conv<<<1024, 256, 0, stream>>>(hs, W, bias, ys, hs_b, w_b, gbias, out);
    gemm_se<<<dim3(64, NCB + 1), 256, 0, stream>>>(hs_b, w_b, ys, bias, gbias, sep, glg2);
    lse_norm<<<Mtot / 64, 256, 0, stream>>>(sep, glg2);   // glg2 -> linear probs in place
    ctc_fwd<<<Bn, 256, 0, stream>>>(glg2, ys, hlens, ylens, out);
}

// Round 5
// 117.403 us; speedup vs baseline: 1.3197x; 1.0315x over previous
//
#include <hip/hip_runtime.h>

constexpr int Bn = 16;
constexpr int Tn = 512;
constexpr int Dn = 256;
constexpr int Vn = 4233;
constexpr int Vp = 4352;   // V padded to 34*128 (rows 4233.. are zeros)
constexpr int Ln = 64;     // LMAX
constexpr int Un = 80;     // glg2/pmat row stride (65 used)
constexpr int CS = 68;     // ctc LDS row stride in floats
constexpr int NCB = 34;    // number of 128-wide vocab column blocks
constexpr int Mtot = Bn * Tn;  // 8192

#define LN2     0.6931471805599453f
#define INV_LN2 1.4426950408889634f

typedef __attribute__((ext_vector_type(8))) short short8;
typedef __attribute__((ext_vector_type(4))) float f32x4;

__device__ __forceinline__ float lg2(float x) { return __builtin_amdgcn_logf(x); }
__device__ __forceinline__ float ex2(float x) { return __builtin_amdgcn_exp2f(x); }

__device__ __forceinline__ unsigned short cvt_bf16(float f) {
    unsigned int u = __float_as_uint(f);
    u = (u + 0x7fffu + ((u >> 16) & 1u)) >> 16;
    return (unsigned short)u;
}

// async global->LDS, 16B per lane; LDS dest contiguous per lane, global addr per-lane
__device__ __forceinline__ void gl_lds16(const void* g, void* l) {
    __builtin_amdgcn_global_load_lds(
        (const __attribute__((address_space(1))) void*)g,
        (__attribute__((address_space(3))) void*)l,
        16, 0, 0);
}

// f64 value from lane-1 (wave_shr:1); lane 0 takes 0.0
__device__ __forceinline__ double dpp_shr1_d(double v) {
    union { double d; int i[2]; } u, r;
    u.d = v;
    r.i[0] = __builtin_amdgcn_update_dpp(0, u.i[0], 0x138, 0xF, 0xF, false);
    r.i[1] = __builtin_amdgcn_update_dpp(0, u.i[1], 0x138, 0xF, 0xF, false);
    return r.d;
}

// wave-wide int max -> uniform value in all lanes (4 DPP stages + 4 readlanes)
__device__ __forceinline__ int wave_imax(int v) {
    int t;
    t = __builtin_amdgcn_update_dpp(v, v, 0xB1,  0xF, 0xF, false); v = (t > v) ? t : v; // xor1
    t = __builtin_amdgcn_update_dpp(v, v, 0x4E,  0xF, 0xF, false); v = (t > v) ? t : v; // xor2
    t = __builtin_amdgcn_update_dpp(v, v, 0x141, 0xF, 0xF, false); v = (t > v) ? t : v; // xor4
    t = __builtin_amdgcn_update_dpp(v, v, 0x140, 0xF, 0xF, false); v = (t > v) ? t : v; // xor8
    int a = __builtin_amdgcn_readlane(v, 0);
    int b = __builtin_amdgcn_readlane(v, 16);
    int c = __builtin_amdgcn_readlane(v, 32);
    int d = __builtin_amdgcn_readlane(v, 48);
    int ab = (a > b) ? a : b;
    int cd = (c > d) ? c : d;
    return (ab > cd) ? ab : cd;
}

// ---------------- conversion prep (zeroes d_out) ----------------
__global__ __launch_bounds__(256) void conv(
    const float* __restrict__ hs, const float* __restrict__ W,
    const float* __restrict__ bias, const int* __restrict__ ys,
    unsigned short* __restrict__ hs_b, unsigned short* __restrict__ w_b,
    float* __restrict__ gbias, float* __restrict__ out)
{
    const int gid = blockIdx.x * 256 + threadIdx.x;
    const int stride = gridDim.x * 256;
    const float4* hs4 = (const float4*)hs;
    const float4* W4  = (const float4*)W;

    if (gid == 0) out[0] = 0.0f;   // atomic target for ctc_fwd

    for (int i = gid; i < (Bn * Tn * Dn) / 4; i += stride) {
        float4 v = hs4[i];
        ushort4 o = make_ushort4(cvt_bf16(v.x), cvt_bf16(v.y), cvt_bf16(v.z), cvt_bf16(v.w));
        *(ushort4*)(&hs_b[i * 4]) = o;
    }
    for (int i = gid; i < Vp * (Dn / 4); i += stride) {
        int row = i >> 6;
        float4 v = make_float4(0.f, 0.f, 0.f, 0.f);
        if (row < Vn) v = W4[i];
        ushort4 o = make_ushort4(cvt_bf16(v.x), cvt_bf16(v.y), cvt_bf16(v.z), cvt_bf16(v.w));
        *(ushort4*)(&w_b[i * 4]) = o;
    }
    for (int i = gid; i < Bn * 128; i += stride) {
        int b = i >> 7;
        int u = i & 127;
        int v = (u == 0) ? 0 : ((u <= Ln) ? ys[b * Ln + u - 1] : -1);
        gbias[i] = (v >= 0) ? bias[v] : 0.0f;
    }
}

// ---------------- unified GEMM ----------------
__global__ __launch_bounds__(256) void gemm_se(
    const unsigned short* __restrict__ hs_b, const unsigned short* __restrict__ w_b,
    const int* __restrict__ ys, const float* __restrict__ bias,
    const float* __restrict__ gbias, float* __restrict__ sep,
    float* __restrict__ glg2)
{
    __shared__ __align__(16) short lsA[128 * 64];
    __shared__ __align__(16) short lsB[128 * 64];

    const int tid = threadIdx.x;
    const int lane = tid & 63;
    const int w = tid >> 6;
    const int lr = lane & 15;
    const int kq = lane >> 4;
    const int m0 = blockIdx.x * 128;
    const int mw = w * 32;
    const bool gather = (blockIdx.y == NCB);
    const int b = blockIdx.x >> 2;

    const int srow = lane >> 3;
    const int scg  = (lane & 7) ^ (srow & 7);
    const int scol = scg * 8;

    const unsigned short* bptr[4];
    #pragma unroll
    for (int j = 0; j < 4; ++j) {
        int c = w * 4 + j;
        int row = c * 8 + srow;
        int v;
        if (gather) {
            if (row == 0) v = 0;
            else if (row <= Ln) v = ys[b * Ln + row - 1];
            else v = Vn + 32;                 // zero pad row of w_b
        } else {
            v = blockIdx.y * 128 + row;
        }
        bptr[j] = w_b + (size_t)v * Dn + scol;
    }

    f32x4 acc[2][8];
    #pragma unroll
    for (int mf = 0; mf < 2; ++mf)
        #pragma unroll
        for (int nf = 0; nf < 8; ++nf)
            acc[mf][nf] = (f32x4){0.f, 0.f, 0.f, 0.f};

    for (int ks = 0; ks < 4; ++ks) {
        const int k0 = ks * 64;
        __syncthreads();
        #pragma unroll
        for (int j = 0; j < 4; ++j) {
            int c = w * 4 + j;
            int row = c * 8 + srow;
            gl_lds16(hs_b + (size_t)(m0 + row) * Dn + k0 + scol, (char*)lsA + c * 1024);
            gl_lds16(bptr[j] + k0,                               (char*)lsB + c * 1024);
        }
        __syncthreads();

        #pragma unroll
        for (int sub = 0; sub < 2; ++sub) {
            short8 af[2], bf[8];
            #pragma unroll
            for (int mf = 0; mf < 2; ++mf) {
                int row = mw + mf * 16 + lr;
                int cg = (sub * 4 + kq) ^ (row & 7);
                af[mf] = *(const short8*)(&lsA[row * 64 + cg * 8]);
            }
            #pragma unroll
            for (int nf = 0; nf < 8; ++nf) {
                int row = nf * 16 + lr;
                int cg = (sub * 4 + kq) ^ (row & 7);
                bf[nf] = *(const short8*)(&lsB[row * 64 + cg * 8]);
            }
            #pragma unroll
            for (int mf = 0; mf < 2; ++mf)
                #pragma unroll
                for (int nf = 0; nf < 8; ++nf)
                    acc[mf][nf] = __builtin_amdgcn_mfma_f32_16x16x32_bf16(
                        af[mf], bf[nf], acc[mf][nf], 0, 0, 0);
        }
    }

    if (!gather) {
        const int n0 = blockIdx.y * 128;
        float bcol[8]; bool valid[8];
        #pragma unroll
        for (int nf = 0; nf < 8; ++nf) {
            int col = n0 + nf * 16 + lr;
            valid[nf] = (col < Vn);
            bcol[nf] = valid[nf] ? bias[col] : 0.0f;
        }
        #pragma unroll
        for (int mf = 0; mf < 2; ++mf) {
            #pragma unroll
            for (int r = 0; r < 4; ++r) {
                float s = 0.0f;
                #pragma unroll
                for (int nf = 0; nf < 8; ++nf)
                    if (valid[nf]) s += __expf(acc[mf][nf][r] + bcol[nf]);
                #pragma unroll
                for (int off = 1; off < 16; off <<= 1) s += __shfl_xor(s, off, 64);
                if (lr == 0)
                    sep[(size_t)blockIdx.y * Mtot + m0 + mw + mf * 16 + kq * 4 + r] = s;
            }
        }
    } else {
        #pragma unroll
        for (int mf = 0; mf < 2; ++mf) {
            #pragma unroll
            for (int nf = 0; nf < 5; ++nf) {
                int u = nf * 16 + lr;
                float gv = gbias[b * 128 + u];
                #pragma unroll
                for (int r = 0; r < 4; ++r) {
                    int g = m0 + mw + mf * 16 + kq * 4 + r;
                    glg2[(size_t)g * Un + u] = (acc[mf][nf][r] + gv) * INV_LN2;
                }
            }
        }
    }
}

// ---------------- CTC forward (f64 chain, unnormalized) + normalizer ----------------
// Blocks 0..15 : f64 chain for batch b on RAW glg2 (log2-units, unnormalized):
//   stage u = exp2(glg2) into LDS (ex2 rides the prefetch path, off the chain);
//   wave-uniform renorm every 32 steps; readout adds -ll_unnorm/Bn.
// Blocks 16..31: normalizer for batch b: corr = sum_{t<hl} log2(Z_t) from sep;
//   adds +corr*ln2/Bn. Loss total = -(ll_unnorm - ln2*corr)/Bn summed over b.
// This replaces the lse_norm kernel (one full RMW pass over glg2 + a launch).
__global__ __launch_bounds__(256) void ctc_fwd(
    const float* __restrict__ pmat, const float* __restrict__ sep,
    const int* __restrict__ ys, const int* __restrict__ hlens,
    const int* __restrict__ ylens, float* __restrict__ out)
{
    __shared__ __align__(16) union SMem {
        struct {
            float ls[2][64 * CS + 4];
            double shO[64], shE[64], shZ[64];
            int   shX[64];
        } c;
        struct { float wsum[4]; } r;
    } sm;

    const int tid = threadIdx.x;
    const int l = tid & 63;
    const int w = tid >> 6;

    if (blockIdx.x >= 16) {
        // ================= normalizer role =================
        const int b = blockIdx.x - 16;
        const int hl = hlens[b];
        float corrAcc = 0.0f;
        #pragma unroll
        for (int j = 0; j < 2; ++j) {
            int t = tid + j * 256;
            float s = 0.0f;
            #pragma unroll
            for (int c = 0; c < NCB; ++c)
                s += sep[(size_t)c * Mtot + b * Tn + t];
            if (t < hl) corrAcc += lg2(s);
        }
        #pragma unroll
        for (int off = 1; off < 64; off <<= 1) corrAcc += __shfl_xor(corrAcc, off, 64);
        if (l == 0) sm.r.wsum[w] = corrAcc;
        __syncthreads();
        if (tid == 0)
            atomicAdd(out, (sm.r.wsum[0] + sm.r.wsum[1] + sm.r.wsum[2] + sm.r.wsum[3])
                           * (LN2 / (float)Bn));
        return;
    }

    // ================= chain role =================
    const int b = blockIdx.x;
    const int hl = hlens[b];
    int yl  = ys[b * Ln + l];
    int ylm = (l >= 1) ? ys[b * Ln + l - 1] : -1;
    const double aF = ((l >= 1) && (yl != ylm)) ? 1.0 : 0.0;

    const float* pm = pmat + (size_t)b * Tn * Un;

    // stage chunk 0 (row tt <-> t = 1 + tt), applying exp2 on the fly
    #pragma unroll
    for (int j = 0; j < 4; ++j) {
        int i = tid + j * 256;
        int tt = i >> 4, u4 = (i & 15) * 4;
        float4 v = *(const float4*)(pm + (size_t)(1 + tt) * Un + u4);
        v.x = ex2(v.x); v.y = ex2(v.y); v.z = ex2(v.z); v.w = ex2(v.w);
        *(float4*)(&sm.c.ls[0][tt * CS + u4]) = v;
    }
    if (tid < 64) sm.c.ls[0][tid * CS + 64] = ex2(pm[(size_t)(1 + tid) * Un + 64]);
    __syncthreads();

    // t=0 init (uniform scale 0); unnormalized
    double o = (l == 0) ? (double)ex2(pm[1]) : 0.0;
    double e = (l == 0) ? (double)ex2(pm[0]) : 0.0;
    double z = 0.0;
    int ex = 0;

    float4 r4a = make_float4(0.f,0.f,0.f,0.f), r4b = r4a, r4c = r4a, r4d = r4a;
    float r1 = 0.0f;

    double qa0, qa1, qa2, qa3, ra0, ra1, ra2, ra3;
    double qb0, qb1, qb2, qb3, rb0, rb1, rb2, rb3;
    double qc0, qc1, qc2, qc3, rc0, rc1, rc2, rc3;

// wave-uniform renorm: scale all lanes by 2^-km, km = max lane exponent
#define RENORM32 do { \
        double mm = fmax(fmax(o, e), z); \
        union { double d; unsigned int ui[2]; } um; um.d = mm; \
        int kk = (int)((um.ui[1] >> 20) & 2047u) - 1023; \
        int km = wave_imax(kk); \
        o = ldexp(o, -km); e = ldexp(e, -km); z = ldexp(z, -km); \
        ex += km; \
    } while (0)

#define STEPR(qv, rv) do { \
        double an = dpp_shr1_d(o); \
        double nO = fma(aF, an, o + e) * (rv); \
        double nE = (e + an) * (qv); \
        double nZ = (z + o) * (qv); \
        o = nO; e = nE; z = nZ; \
    } while (0)

#define LDA(base) do { \
        qa0 = (double)buf[(base) * CS];       ra0 = (double)buf[(base) * CS + 1 + l]; \
        qa1 = (double)buf[((base)+1) * CS];   ra1 = (double)buf[((base)+1) * CS + 1 + l]; \
        qa2 = (double)buf[((base)+2) * CS];   ra2 = (double)buf[((base)+2) * CS + 1 + l]; \
        qa3 = (double)buf[((base)+3) * CS];   ra3 = (double)buf[((base)+3) * CS + 1 + l]; \
    } while (0)
#define LDB(base) do { \
        qb0 = (double)buf[(base) * CS];       rb0 = (double)buf[(base) * CS + 1 + l]; \
        qb1 = (double)buf[((base)+1) * CS];   rb1 = (double)buf[((base)+1) * CS + 1 + l]; \
        qb2 = (double)buf[((base)+2) * CS];   rb2 = (double)buf[((base)+2) * CS + 1 + l]; \
        qb3 = (double)buf[((base)+3) * CS];   rb3 = (double)buf[((base)+3) * CS + 1 + l]; \
    } while (0)
#define LDC(base) do { \
        qc0 = (double)buf[(base) * CS];       rc0 = (double)buf[(base) * CS + 1 + l]; \
        qc1 = (double)buf[((base)+1) * CS];   rc1 = (double)buf[((base)+1) * CS + 1 + l]; \
        qc2 = (double)buf[((base)+2) * CS];   rc2 = (double)buf[((base)+2) * CS + 1 + l]; \
        qc3 = (double)buf[((base)+3) * CS];   rc3 = (double)buf[((base)+3) * CS + 1 + l]; \
    } while (0)

#define W4A do { STEPR(qa0,ra0); STEPR(qa1,ra1); STEPR(qa2,ra2); STEPR(qa3,ra3); } while (0)
#define W4B do { STEPR(qb0,rb0); STEPR(qb1,rb1); STEPR(qb2,rb2); STEPR(qb3,rb3); } while (0)
#define W4C do { STEPR(qc0,rc0); STEPR(qc1,rc1); STEPR(qc2,rc2); STEPR(qc3,rc3); } while (0)

// predicated fallback step (partial chunks; never taken when hl == Tn).
// Wave-uniform scale + uniform ex compensate exactly at readout, so freezing
// is preserved.
#define STEPS(Joff, ACT) do { \
        RENORM32; \
        double q = (double)buf[(Joff) * CS]; \
        double r = (double)buf[(Joff) * CS + 1 + l]; \
        double an = dpp_shr1_d(o); \
        double nO = fma(aF, an, o + e) * r; \
        double nE = (e + an) * q; \
        double nZ = (z + o) * q; \
        bool act = (ACT); \
        o = act ? nO : o; e = act ? nE : e; z = act ? nZ : z; \
    } while (0)

    for (int c = 0; c < 8; ++c) {
        if (c < 7) {
            const int tb = 1 + (c + 1) * 64;
            { int i = tid;       int tt = i >> 4, u4 = (i & 15) * 4;
              r4a = (tb + tt < Tn) ? *(const float4*)(pm + (size_t)(tb + tt) * Un + u4) : make_float4(0.f,0.f,0.f,0.f); }
            { int i = tid + 256; int tt = i >> 4, u4 = (i & 15) * 4;
              r4b = (tb + tt < Tn) ? *(const float4*)(pm + (size_t)(tb + tt) * Un + u4) : make_float4(0.f,0.f,0.f,0.f); }
            { int i = tid + 512; int tt = i >> 4, u4 = (i & 15) * 4;
              r4c = (tb + tt < Tn) ? *(const float4*)(pm + (size_t)(tb + tt) * Un + u4) : make_float4(0.f,0.f,0.f,0.f); }
            { int i = tid + 768; int tt = i >> 4, u4 = (i & 15) * 4;
              r4d = (tb + tt < Tn) ? *(const float4*)(pm + (size_t)(tb + tt) * Un + u4) : make_float4(0.f,0.f,0.f,0.f); }
            if (tid < 64)
                r1 = (tb + tid < Tn) ? pm[(size_t)(tb + tid) * Un + 64] : 0.0f;
        }

        const float* buf = sm.c.ls[c & 1];

        if (c < 7) {
            if (hl >= (c + 1) * 64 + 1) {
                RENORM32;
                LDA(0); LDB(4);
                LDC(8);  W4A;     // w0  rows 0-3
                LDA(12); W4B;     // w1  rows 4-7
                LDB(16); W4C;     // w2  rows 8-11
                LDC(20); W4A;     // w3  rows 12-15
                LDA(24); W4B;     // w4  rows 16-19
                LDB(28); W4C;     // w5  rows 20-23
                LDC(32); W4A;     // w6  rows 24-27
                LDA(36); W4B;     // w7  rows 28-31
                RENORM32;
                LDB(40); W4C;     // w8  rows 32-35
                LDC(44); W4A;     // w9  rows 36-39
                LDA(48); W4B;     // w10 rows 40-43
                LDB(52); W4C;     // w11 rows 44-47
                LDC(56); W4A;     // w12 rows 48-51
                LDA(60); W4B;     // w13 rows 52-55
                W4C;              // w14 rows 56-59
                W4A;              // w15 rows 60-63
            } else {
                #pragma unroll 1
                for (int j = 0; j < 64; ++j)
                    STEPS(j, (c * 64 + 1 + j) < hl);
            }
        } else {
            if (hl >= Tn) {
                RENORM32;
                LDA(0); LDB(4);
                LDC(8);  W4A;
                LDA(12); W4B;
                LDB(16); W4C;
                LDC(20); W4A;
                LDA(24); W4B;
                LDB(28); W4C;
                LDC(32); W4A;
                LDA(36); W4B;
                RENORM32;
                LDB(40); W4C;
                LDC(44); W4A;
                LDA(48); W4B;
                LDB(52); W4C;
                LDC(56); W4A;
                LDA(60); W4B;
                W4C;                               // w14 rows 56-59
                STEPR(qa0, ra0); STEPR(qa1, ra1); STEPR(qa2, ra2);  // rows 60-62
            } else {
                #pragma unroll 1
                for (int j = 0; j < 63; ++j)
                    STEPS(j, (449 + j) < hl);
            }
        }

        if (c < 7) {
            const int tb = 1 + (c + 1) * 64;
            float* dst = sm.c.ls[(c + 1) & 1];
            { int i = tid;       int tt = i >> 4, u4 = (i & 15) * 4; float4 v = r4a;
              v.x = ex2(v.x); v.y = ex2(v.y); v.z = ex2(v.z); v.w = ex2(v.w);
              if (tb + tt >= Tn) v = make_float4(0.f,0.f,0.f,0.f);
              *(float4*)(&dst[tt * CS + u4]) = v; }
            { int i = tid + 256; int tt = i >> 4, u4 = (i & 15) * 4; float4 v = r4b;
              v.x = ex2(v.x); v.y = ex2(v.y); v.z = ex2(v.z); v.w = ex2(v.w);
              if (tb + tt >= Tn) v = make_float4(0.f,0.f,0.f,0.f);
              *(float4*)(&dst[tt * CS + u4]) = v; }
            { int i = tid + 512; int tt = i >> 4, u4 = (i & 15) * 4; float4 v = r4c;
              v.x = ex2(v.x); v.y = ex2(v.y); v.z = ex2(v.z); v.w = ex2(v.w);
              if (tb + tt >= Tn) v = make_float4(0.f,0.f,0.f,0.f);
              *(float4*)(&dst[tt * CS + u4]) = v; }
            { int i = tid + 768; int tt = i >> 4, u4 = (i & 15) * 4; float4 v = r4d;
              v.x = ex2(v.x); v.y = ex2(v.y); v.z = ex2(v.z); v.w = ex2(v.w);
              if (tb + tt >= Tn) v = make_float4(0.f,0.f,0.f,0.f);
              *(float4*)(&dst[tt * CS + u4]) = v; }
            if (tid < 64)
                dst[tid * CS + 64] = (tb + tid < Tn) ? ex2(r1) : 0.0f;
        }
        __syncthreads();
    }
#undef RENORM32
#undef STEPR
#undef LDA
#undef LDB
#undef LDC
#undef W4A
#undef W4B
#undef W4C
#undef STEPS

    if (tid < 64) { sm.c.shO[l] = o; sm.c.shE[l] = e; sm.c.shZ[l] = z; sm.c.shX[l] = ex; }
    __syncthreads();

    if (tid == 0) {
        int L = ylens[b];
        double vo = sm.c.shO[L - 1]; int xo = sm.c.shX[L - 1];   // alpha[2L-1]
        double ve; int xe;                                        // alpha[2L]
        if (L == 64) { ve = sm.c.shZ[63]; xe = sm.c.shX[63]; }
        else         { ve = sm.c.shE[L];  xe = sm.c.shX[L]; }
        int em = (xo > xe) ? xo : xe;
        double s = ldexp(vo, xo - em) + ldexp(ve, xe - em);
        union { double d; unsigned int ui[2]; } us; us.d = s;
        int ks = (int)((us.ui[1] >> 20) & 2047u) - 1023;
        double mant = ldexp(s, -ks);                      // in [1,2)
        float ll = (lg2((float)mant) + (float)(ks + em)) * LN2;  // unnormalized
        atomicAdd(out, -ll / (float)Bn);
    }
}

extern "C" void kernel_launch(void* const* d_in, const int* in_sizes, int n_in,
                              void* d_out, int out_size, void* d_ws, size_t ws_size,
                              hipStream_t stream) {
    const float* hs    = (const float*)d_in[0];
    const int*   hlens = (const int*)d_in[1];
    const int*   ys    = (const int*)d_in[2];
    const int*   ylens = (const int*)d_in[3];
    const float* W     = (const float*)d_in[4];
    const float* bias  = (const float*)d_in[5];
    float* out = (float*)d_out;

    char* ws = (char*)d_ws;
    unsigned short* hs_b = (unsigned short*)(ws);                       // 4,194,304 B
    unsigned short* w_b  = (unsigned short*)(ws + 4194304);             // 2,228,224 B
    float* glg2  = (float*)(ws + 6422528);                              // 2,621,440 B
    float* sep   = (float*)(ws + 9043968);                              // 1,114,112 B
    float* gbias = (float*)(ws + 10158080);                             //     8,192 B

    conv<<<1024, 256, 0, stream>>>(hs, W, bias, ys, hs_b, w_b, gbias, out);
    gemm_se<<<dim3(64, NCB + 1), 256, 0, stream>>>(hs_b, w_b, ys, bias, gbias, sep, glg2);
    ctc_fwd<<<32, 256, 0, stream>>>(glg2, sep, ys, hlens, ylens, out);
}